// Round 12
// baseline (760.713 us; speedup 1.0000x reference)
//
#include <hip/hip_runtime.h>
#include <math.h>

typedef unsigned short u16;
typedef unsigned int u32;
typedef float f32x4 __attribute__((ext_vector_type(4)));
typedef __bf16 bf16x8 __attribute__((ext_vector_type(8)));

#define NTOK 57800   // B*N
#define NSEQ 7225
#define NBATCH 8

static __device__ __forceinline__ float bf2f(u16 u){ u32 x=((u32)u)<<16; float f; __builtin_memcpy(&f,&x,4); return f; }
// f32->bf16 RNE via hardware convert
static __device__ __forceinline__ u16 f2bf(float f){ __bf16 h = (__bf16)f; u16 u; __builtin_memcpy(&u,&h,2); return u; }
// fast gelu: 0.5*v*(1+tanh(y)) == v*sigmoid(2y); ~8 VALU ops, no branch
static __device__ __forceinline__ float gelu_f(float v){
  float t = v * v;
  float w = fmaf(t, -0.07135481627f, -1.5957691216f);
  float e = __expf(w * v);
  return v * __builtin_amdgcn_rcpf(1.0f + e);
}

static __device__ __forceinline__ void gl16(const u16* g, u16* l){
  __builtin_amdgcn_global_load_lds((const __attribute__((address_space(1))) void*)g,
                                   (__attribute__((address_space(3))) void*)l, 16, 0, 0);
}

// broadcast lane 'lane' of v to all lanes (lane uniform / compile-time)
static __device__ __forceinline__ float rdlane(float v, int lane){
  int i; __builtin_memcpy(&i,&v,4);
  int r = __builtin_amdgcn_readlane(i, lane);
  float f; __builtin_memcpy(&f,&r,4);
  return f;
}

// ---------- batched LDS-tiled weight transpose + bf16 cast: dst[n*K+k] = src[k*N+n] ----------
struct WJobs { const float* src[10]; u16* dst[10]; int K[10]; int N[10]; };
__global__ __launch_bounds__(256) void wtrans_all(WJobs j){
  int z = blockIdx.z;
  int K = j.K[z], N = j.N[z];
  int bk = blockIdx.x*32, bn = blockIdx.y*32;
  if (bk >= K || bn >= N) return;
  const float* src = j.src[z];
  u16* dst = j.dst[z];
  __shared__ float t[32][33];
  int tx = threadIdx.x&31, ty = threadIdx.x>>5;
  #pragma unroll
  for (int u=0;u<4;u++){
    int k = bk+ty+u*8, n = bn+tx;
    if (k<K && n<N) t[ty+u*8][tx] = src[(long)k*N+n];
  }
  __syncthreads();
  #pragma unroll
  for (int u=0;u<4;u++){
    int n = bn+ty+u*8, k = bk+tx;
    if (n<N && k<K) dst[(long)n*K+k] = f2bf(t[tx][ty+u*8]);
  }
}

// ---------- LayerNorm (rows x 256) fp32 -> bf16, one wave per row ----------
__global__ __launch_bounds__(256) void ln_kernel(const float* __restrict__ in, const float* __restrict__ g,
                                                 const float* __restrict__ b, u16* __restrict__ out, int rows){
  int wid = threadIdx.x>>6, lane = threadIdx.x&63;
  int row = blockIdx.x*4 + wid;
  if (row >= rows) return;
  const float4 xv = *reinterpret_cast<const float4*>(in + (long)row*256 + lane*4);
  float s = xv.x+xv.y+xv.z+xv.w;
  float s2 = xv.x*xv.x+xv.y*xv.y+xv.z*xv.z+xv.w*xv.w;
  #pragma unroll
  for (int o=32;o;o>>=1){ s += __shfl_xor(s,o,64); s2 += __shfl_xor(s2,o,64); }
  float mean = s*(1.f/256.f);
  float var = fmaxf(s2*(1.f/256.f) - mean*mean, 0.f);
  float rstd = rsqrtf(var + 1e-5f);
  float4 gv = *reinterpret_cast<const float4*>(g + lane*4);
  float4 bv = *reinterpret_cast<const float4*>(b + lane*4);
  ushort4 o4;
  o4.x = f2bf((xv.x-mean)*rstd*gv.x + bv.x);
  o4.y = f2bf((xv.y-mean)*rstd*gv.y + bv.y);
  o4.z = f2bf((xv.z-mean)*rstd*gv.z + bv.z);
  o4.w = f2bf((xv.w-mean)*rstd*gv.w + bv.w);
  *reinterpret_cast<ushort4*>(out + (long)row*256 + lane*4) = o4;
}

// ---------- bf16 MFMA GEMM v8: C = A[M,K] @ Bt[N,K]^T ----------
// 128x128 tile, 8 waves (512 thr, 64x32/wave), BK=32, 4 LDS buffers (64 KB) ->
// 2 blocks/CU (16 waves/CU). 3-tile-deep counted-vmcnt prefetch (T4/m201):
// prologue stages 3 tiles; per tile: wait vmcnt(4) (this tile drained, 2 more
// tiles' loads stay in flight), ONE raw barrier, then immediately stage t+3
// into the buffer freed by compute(t-1), then 16 MFMA. ~3 iterations of HBM
// latency coverage. K consumed in ascending order, same per-output MFMA
// sequence as before -> bit-identical results. Swizzle layout = R9-verified:
// store-side slot^=(row>>1)&3 via pre-swizzled global src, matching read XOR.
template<bool BIASF, bool RESF, bool GELUF, bool OF32, bool OBF16>
__global__ __launch_bounds__(512) void gemm3(const u16* __restrict__ A, const u16* __restrict__ Bt,
    const float* __restrict__ bias, const float* __restrict__ resid,
    float* __restrict__ outF, u16* __restrict__ outB,
    int M, int N, int K, int gn, long aB, long bB, long cB)
{
  __shared__ __align__(16) u16 lds[4][2][4096];   // [buf][A/B][128*32] = 64 KB
  int nwg = gridDim.x, bid = blockIdx.x;
  int qx = nwg>>3, rx = nwg&7;
  int xcd = bid&7, lin = bid>>3;
  int swz = (xcd<rx)? (xcd*(qx+1)+lin) : (rx + xcd*qx + lin);  // bijective (m204)
  int mi_ = swz/gn;
  int m0 = mi_*128, n0 = (swz - mi_*gn)*128;

  const u16* Ab  = A  + (long)blockIdx.z*aB;
  const u16* Btb = Bt + (long)blockIdx.z*bB;
  long coff = (long)blockIdx.z*cB;
  int tid = threadIdx.x, w = tid>>6, l = tid&63;
  int srow = w*16 + (l>>2);                       // staging row (16 rows/wave)
  int csrc = (((l&3) ^ ((l>>3)&3)) << 3);         // pre-swizzled global k-elem offset
  int l15 = l&15, lq = l>>4;
  int wm = (w>>2)*64, wn = (w&3)*32;              // 2M x 4N waves, 64x32 per wave
  int sxr = (l15>>1)&3;                           // read-slot XOR term

  f32x4 acc[4][2];
  #pragma unroll
  for (int a=0;a<4;a++)
    #pragma unroll
    for (int b2=0;b2<2;b2++)
      #pragma unroll
      for (int r2=0;r2<4;r2++) acc[a][b2][r2]=0.f;

  int nt = K>>5;

  auto STAGE = [&](int k0, int bufi){
    gl16(Ab  + (long)(m0+srow)*K + k0 + csrc, &lds[bufi][0][0] + w*512 + l*8);
    gl16(Btb + (long)(n0+srow)*K + k0 + csrc, &lds[bufi][1][0] + w*512 + l*8);
  };

  int npro = (nt < 3) ? nt : 3;
  for (int p=0; p<npro; p++) STAGE(p<<5, p);

  for (int t=0; t<nt; t++){
    int cur = t&3;
    int ahead = nt-1-t; if (ahead > 2) ahead = 2;
    // drain only THIS tile's 2 loads; up to 2 more tiles' loads keep flying (T4).
    if (ahead == 2)      asm volatile("s_waitcnt vmcnt(4)" ::: "memory");
    else if (ahead == 1) asm volatile("s_waitcnt vmcnt(2)" ::: "memory");
    else                 asm volatile("s_waitcnt vmcnt(0)" ::: "memory");
    __builtin_amdgcn_s_barrier();
    __builtin_amdgcn_sched_barrier(0);
    // stage tile t+3 into buf[(t+3)&3] = buf[(t-1)&3]; safe: the barrier above
    // proves all waves finished compute(t-1), the last reader of that buffer.
    if (t+3 < nt) STAGE((t+3)<<5, (t+3)&3);
    {
      bf16x8 af[4], bfv[2];
      int ko = (lq ^ sxr) << 3;                   // swizzled k-slot (8-elem units)
      #pragma unroll
      for (int mi=0;mi<4;mi++)
        af[mi]  = *reinterpret_cast<const bf16x8*>(&lds[cur][0][0] + (wm+mi*16+l15)*32 + ko);
      #pragma unroll
      for (int ni=0;ni<2;ni++)
        bfv[ni] = *reinterpret_cast<const bf16x8*>(&lds[cur][1][0] + (wn+ni*16+l15)*32 + ko);
      #pragma unroll
      for (int mi=0;mi<4;mi++)
        #pragma unroll
        for (int ni=0;ni<2;ni++)
          acc[mi][ni] = __builtin_amdgcn_mfma_f32_16x16x32_bf16(bfv[ni], af[mi], acc[mi][ni], 0,0,0);
    }
  }

  #pragma unroll
  for (int mi=0;mi<4;mi++){
    int row = m0 + wm + mi*16 + l15;
    if (row >= M) continue;
    #pragma unroll
    for (int ni=0;ni<2;ni++){
      int col0 = n0 + wn + ni*16 + lq*4;
      if (col0 >= N) continue;
      f32x4 v = acc[mi][ni];
      if (BIASF){
        const float4 bv = *reinterpret_cast<const float4*>(bias + col0);
        v[0]+=bv.x; v[1]+=bv.y; v[2]+=bv.z; v[3]+=bv.w;
      }
      long idx = (long)row*N + col0;
      if (RESF){
        const float4 rv = *reinterpret_cast<const float4*>(resid + coff + idx);
        v[0]+=rv.x; v[1]+=rv.y; v[2]+=rv.z; v[3]+=rv.w;
      }
      if (GELUF){
        #pragma unroll
        for (int r2=0;r2<4;r2++) v[r2] = gelu_f(v[r2]);
      }
      if (OF32){
        float4 o; o.x=v[0]; o.y=v[1]; o.z=v[2]; o.w=v[3];
        *reinterpret_cast<float4*>(outF + coff + idx) = o;
      }
      if (OBF16){
        ushort4 o; o.x=f2bf(v[0]); o.y=f2bf(v[1]); o.z=f2bf(v[2]); o.w=f2bf(v[3]);
        *reinterpret_cast<ushort4*>(outB + coff + idx) = o;
      }
    }
  }
}

// ---------- ctx[b,h,d,e] partials + fused k colsum partials ----------
// 16-row tiles, uint2 (4x bf16, 8B/lane) staging loads; same n-ascending
// accumulation order as the 8-row scalar version -> bit-identical.
__global__ __launch_bounds__(256) void ctx_part(const u16* __restrict__ qkvb, float* __restrict__ part,
                                                float* __restrict__ spart2){
  int ch = blockIdx.x, bh = blockIdx.y; int b = bh>>3, h = bh&7;
  __shared__ float ek[16][32], vl[16][32];
  int tid = threadIdx.x;
  int d = tid&31, eg = (tid>>5)*4;
  float acc[4] = {0.f,0.f,0.f,0.f};
  float ssum = 0.f;
  int n0 = ch*226; int n1 = n0+226; if (n1 > NSEQ) n1 = NSEQ;
  int lr = tid>>4, le = (tid&15)*4;            // row 0..15, elem-quad 0..60
  for (int nb=n0; nb<n1; nb+=16){
    int n = nb + lr;
    float f0=0.f, f1=0.f, f2=0.f, f3=0.f;
    if (n < n1){
      long base = ((long)(b*NSEQ+n))*768 + h*32;
      const u16* src = (le < 32) ? (qkvb + base + 256 + le) : (qkvb + base + 512 + (le-32));
      uint2 pk = *reinterpret_cast<const uint2*>(src);
      f0 = bf2f((u16)(pk.x&0xffffu)); f1 = bf2f((u16)(pk.x>>16));
      f2 = bf2f((u16)(pk.y&0xffffu)); f3 = bf2f((u16)(pk.y>>16));
      if (le < 32){ f0=__expf(f0); f1=__expf(f1); f2=__expf(f2); f3=__expf(f3); }
    }
    if (le < 32){ ek[lr][le]=f0; ek[lr][le+1]=f1; ek[lr][le+2]=f2; ek[lr][le+3]=f3; }
    else        { int vv=le-32; vl[lr][vv]=f0; vl[lr][vv+1]=f1; vl[lr][vv+2]=f2; vl[lr][vv+3]=f3; }
    __syncthreads();
    #pragma unroll
    for (int r=0;r<16;r++){
      float kv = ek[r][d];
      ssum += kv;
      #pragma unroll
      for (int j=0;j<4;j++) acc[j] += kv * vl[r][eg+j];
    }
    __syncthreads();
  }
  #pragma unroll
  for (int j=0;j<4;j++) part[((long)(bh*32+ch))*1024 + d*32 + eg + j] = acc[j];
  if (tid < 32) spart2[(bh*32+ch)*32 + d] = ssum;
}
__global__ void ctx_red(const float* __restrict__ part, const float* __restrict__ spart2,
                        float* __restrict__ ctx){
  int bh = blockIdx.x;
  __shared__ float sinvl[32];
  int tid = threadIdx.x;
  if (tid < 32){
    float s=0.f;
    for (int ch=0;ch<32;ch++) s += spart2[(bh*32+ch)*32 + tid];
    sinvl[tid] = 1.0f/s;
  }
  __syncthreads();
  for (int idx=tid; idx<1024; idx+=256){
    float s=0.f;
    for (int ch=0;ch<32;ch++) s += part[((long)(bh*32+ch))*1024 + idx];
    ctx[(long)bh*1024 + idx] = s * sinvl[idx>>5];
  }
}

// ---------- q feature-softmax: qs[n,c] = exp(q)/sum_head(exp) * DH^-0.5, bf16 out ----------
__global__ __launch_bounds__(256) void qsoftmax(const u16* __restrict__ qkvb, u16* __restrict__ qsb){
  int wid = threadIdx.x>>6, lane = threadIdx.x&63;
  int n = blockIdx.x*4 + wid;
  int b = blockIdx.y;
  if (n >= NSEQ) return;
  const ushort4 qv = *reinterpret_cast<const ushort4*>(qkvb + ((long)(b*NSEQ+n))*768 + lane*4);
  float e0 = __expf(bf2f(qv.x)), e1 = __expf(bf2f(qv.y)),
        e2 = __expf(bf2f(qv.z)), e3 = __expf(bf2f(qv.w));
  float s = e0+e1+e2+e3;
  s += __shfl_xor(s,1,64); s += __shfl_xor(s,2,64); s += __shfl_xor(s,4,64);
  float r = 0.17677669529663687f / s;
  ushort4 o; o.x=f2bf(e0*r); o.y=f2bf(e1*r); o.z=f2bf(e2*r); o.w=f2bf(e3*r);
  *reinterpret_cast<ushort4*>(qsb + ((long)(b*NSEQ+n))*256 + lane*4) = o;
}

// ---------- merged weight: w2bt[b][j][h*32+d] = sum_e ctx[b,h,d,e]*WOT[j][h*32+e] ----------
__global__ __launch_bounds__(256) void ctx_wo(const float* __restrict__ ctx, const u16* __restrict__ wot,
                                              u16* __restrict__ w2bt){
  int jg = blockIdx.x, b = blockIdx.y;
  int j0 = jg*32;
  __shared__ u16 wol[32][256];
  int tid = threadIdx.x;
  {
    int r = tid>>3, c = (tid&7)*32;
    const uint4* src = reinterpret_cast<const uint4*>(wot + (j0+r)*256 + c);
    uint4* dst = reinterpret_cast<uint4*>(&wol[r][c]);
    dst[0]=src[0]; dst[1]=src[1]; dst[2]=src[2]; dst[3]=src[3];
  }
  int h = tid>>5, d = tid&31;
  float creg[32];
  {
    const float4* cp = reinterpret_cast<const float4*>(ctx + (long)(b*8+h)*1024 + d*32);
    #pragma unroll
    for (int u=0;u<8;u++){ float4 v = cp[u]; creg[u*4]=v.x; creg[u*4+1]=v.y; creg[u*4+2]=v.z; creg[u*4+3]=v.w; }
  }
  __syncthreads();
  for (int jj=0;jj<32;jj++){
    const uint4* wp = reinterpret_cast<const uint4*>(&wol[jj][h*32]);
    float acc = 0.f;
    #pragma unroll
    for (int u=0;u<4;u++){
      uint4 wv = wp[u];
      acc += bf2f((u16)(wv.x&0xffffu))*creg[u*8+0] + bf2f((u16)(wv.x>>16))*creg[u*8+1]
           + bf2f((u16)(wv.y&0xffffu))*creg[u*8+2] + bf2f((u16)(wv.y>>16))*creg[u*8+3]
           + bf2f((u16)(wv.z&0xffffu))*creg[u*8+4] + bf2f((u16)(wv.z>>16))*creg[u*8+5]
           + bf2f((u16)(wv.w&0xffffu))*creg[u*8+6] + bf2f((u16)(wv.w>>16))*creg[u*8+7];
    }
    w2bt[((long)b*256 + j0+jj)*256 + tid] = f2bf(acc);
  }
}

// ---------- cov partials: 512 chunks, reg-prefetch dbuf, broadcast-b128 inner ----------
__global__ __launch_bounds__(256) void cov_part(const float* __restrict__ xu, float* __restrict__ part){
  int ch = blockIdx.x;
  __shared__ float xl[2][8][64];
  int tid = threadIdx.x;
  int i = tid&63, jg = (tid>>6)*16;
  int lrow = tid>>5, lcol = (tid&31)*2;
  float acc[16];
  #pragma unroll
  for (int j=0;j<16;j++) acc[j]=0.f;
  int n0 = ch*113;
  const int NT = 15;
  float2 xr2;
  auto LOAD = [&](int t){
    int n = n0 + t*8 + lrow;
    if (n < n0+113 && n < NTOK) xr2 = *reinterpret_cast<const float2*>(xu + (long)n*64 + lcol);
    else { xr2.x = 0.f; xr2.y = 0.f; }
  };
  LOAD(0);
  for (int t=0; t<NT; t++){
    int cur = t&1;
    xl[cur][lrow][lcol] = xr2.x; xl[cur][lrow][lcol+1] = xr2.y;
    __syncthreads();
    if (t+1 < NT) LOAD(t+1);
    #pragma unroll
    for (int r=0;r<8;r++){
      float xv = xl[cur][r][i];
      const float4* fb = reinterpret_cast<const float4*>(&xl[cur][r][jg]);
      float4 f0=fb[0], f1=fb[1], f2=fb[2], f3=fb[3];
      acc[0]+=xv*f0.x; acc[1]+=xv*f0.y; acc[2]+=xv*f0.z; acc[3]+=xv*f0.w;
      acc[4]+=xv*f1.x; acc[5]+=xv*f1.y; acc[6]+=xv*f1.z; acc[7]+=xv*f1.w;
      acc[8]+=xv*f2.x; acc[9]+=xv*f2.y; acc[10]+=xv*f2.z; acc[11]+=xv*f2.w;
      acc[12]+=xv*f3.x; acc[13]+=xv*f3.y; acc[14]+=xv*f3.z; acc[15]+=xv*f3.w;
    }
    __syncthreads();
  }
  #pragma unroll
  for (int j=0;j<16;j++) part[(long)ch*4096 + (jg+j)*64 + i] = acc[j];
}
__global__ void cov_red(const float* __restrict__ part, float* __restrict__ cov){
  __shared__ float red[4][64];
  int o = blockIdx.x*64 + (threadIdx.x&63);
  int sl = threadIdx.x>>6;
  float s=0.f;
  for (int ch=sl; ch<512; ch+=4) s += part[(long)ch*4096 + o];
  if (sl>0) red[sl][threadIdx.x&63] = s;
  __syncthreads();
  if (sl==0){
    s += red[1][threadIdx.x&63] + red[2][threadIdx.x&63] + red[3][threadIdx.x&63];
    cov[o] = s * (1.0f/57800.0f);
  }
}

// ---------- Cholesky of 64x64 + lower-triangular inverse (register-resident) ----------
__global__ __launch_bounds__(64) void chol_inv(const float* __restrict__ cov, float* __restrict__ Linv){
  int t = threadIdx.x;
  float r[64];
  #pragma unroll
  for (int k=0;k<16;k++){
    float4 v4 = *reinterpret_cast<const float4*>(cov + (long)t*64 + k*4);
    r[k*4]=v4.x; r[k*4+1]=v4.y; r[k*4+2]=v4.z; r[k*4+3]=v4.w;
  }
  float dinv[64];
  #pragma unroll
  for (int j=0;j<64;j++){
    float ajj = rdlane(r[j], j);
    float ljj = sqrtf(fmaxf(ajj, 1e-20f));
    float rinv = 1.0f / ljj;
    dinv[j] = rinv;
    float ltj = r[j] * rinv;
    r[j] = ltj;
    #pragma unroll
    for (int k=j+1;k<64;k++){
      float lkj = rdlane(ltj, k);
      r[k] -= ltj * lkj;
    }
  }
  float v[64];
  #pragma unroll
  for (int k=0;k<64;k++) v[k] = (k==t) ? 1.f : 0.f;
  #pragma unroll
  for (int i=0;i<64;i++){
    float xi = v[i] * dinv[i];
    Linv[i*64 + t] = xi;
    #pragma unroll
    for (int k=i+1;k<64;k++){
      v[k] -= rdlane(r[i], k) * xi;
    }
  }
}

// ---------- whiten: xw[n,i] = sum_j x_[n,j]*Linv[i,j]; xws = xw*softplus(mu) ----------
__global__ __launch_bounds__(256) void whiten(const float* __restrict__ xu, const float* __restrict__ Linv,
                                              const float* __restrict__ mu, u16* __restrict__ xw, u16* __restrict__ xws){
  __shared__ float Ll[64][65];
  int tid = threadIdx.x;
  for (int u=0; u<16; u++){ int idx = u*256+tid; Ll[idx>>6][idx&63] = Linv[idx]; }
  __syncthreads();
  int wid = tid>>6, lane = tid&63;
  float m = mu[lane];
  float sp = (m > 20.f)? m : log1pf(expf(m));
  for (int rr=0; rr<4; rr++){
    int row = blockIdx.x*16 + wid*4 + rr;
    if (row >= NTOK) continue;
    float xj = xu[(long)row*64 + lane];
    float s = 0.f;
    #pragma unroll
    for (int j=0;j<64;j++) s += __shfl(xj, j, 64) * Ll[lane][j];
    xw[(long)row*64+lane]  = f2bf(s);
    xws[(long)row*64+lane] = f2bf(s * sp);
  }
}

// ---------- ctx2 partials: one block per (chunk,batch), fx read once; 8 waves ----------
__global__ __launch_bounds__(512) void ctx2_part(const u16* __restrict__ xw, const float* __restrict__ fx,
                                                 float* __restrict__ part){
  int ch = blockIdx.x, b = blockIdx.y;
  __shared__ float xwlf[2][16][64];    // 8 KB
  __shared__ float fxl[2][16][256];    // 32 KB
  int tid = threadIdx.x;
  int p = tid&63, jg = ((tid>>6)&7)*32;       // 8 wave-groups x 32 c = 256
  int lrow = tid>>5, lcol = (tid&31)*8, xcol = (tid&31)*2;
  float acc[32];
  #pragma unroll
  for (int j=0;j<32;j++) acc[j]=0.f;
  int n0 = ch*226;
  int n1 = n0+226; if (n1 > NSEQ) n1 = NSEQ;
  const int NT = 15;                           // 15*16 = 240 >= 226
  float4 fra, frb; u32 xr;
  auto LOAD = [&](int t){
    int n = n0 + t*16 + lrow;
    if (n < n1){
      const float4* fp = reinterpret_cast<const float4*>(fx + ((long)b*NSEQ+n)*256 + lcol);
      fra = fp[0]; frb = fp[1];
      xr = *reinterpret_cast<const u32*>(xw + ((long)b*NSEQ+n)*64 + xcol);
    } else {
      fra.x=0.f; fra.y=0.f; fra.z=0.f; fra.w=0.f;
      frb.x=0.f; frb.y=0.f; frb.z=0.f; frb.w=0.f;
      xr = 0;
    }
  };
  LOAD(0);
  for (int t=0; t<NT; t++){
    int cur = t&1;
    xwlf[cur][lrow][xcol]   = bf2f((u16)(xr&0xffffu));
    xwlf[cur][lrow][xcol+1] = bf2f((u16)(xr>>16));
    *reinterpret_cast<float4*>(&fxl[cur][lrow][lcol])   = fra;
    *reinterpret_cast<float4*>(&fxl[cur][lrow][lcol+4]) = frb;
    __syncthreads();
    if (t+1 < NT) LOAD(t+1);
    #pragma unroll
    for (int r=0;r<16;r++){
      float xv = xwlf[cur][r][p];
      const float4* fb = reinterpret_cast<const float4*>(&fxl[cur][r][jg]);  // wave-uniform -> broadcast
      #pragma unroll
      for (int c4=0;c4<8;c4++){
        float4 f = fb[c4];
        acc[c4*4+0]+=xv*f.x; acc[c4*4+1]+=xv*f.y; acc[c4*4+2]+=xv*f.z; acc[c4*4+3]+=xv*f.w;
      }
    }
    __syncthreads();
  }
  long base = ((long)(b*32+ch)*256 + jg)*64 + p;
  #pragma unroll
  for (int j=0;j<32;j++) part[base + (long)j*64] = acc[j];
}
__global__ void ctx2_red(const float* __restrict__ part, u16* __restrict__ c2t){
  int b = blockIdx.y;
  int idx0 = blockIdx.x*1024 + threadIdx.x;
  #pragma unroll
  for (int u=0;u<4;u++){
    int id = idx0 + u*256;
    float s=0.f;
    for (int ch=0;ch<32;ch++) s += part[(long)(b*32+ch)*16384 + id];
    c2t[(long)b*16384 + id] = f2bf(s);
  }
}

// ===================== host launch =====================
extern "C" void kernel_launch(void* const* d_in, const int* in_sizes, int n_in,
                              void* d_out, int out_size, void* d_ws, size_t ws_size,
                              hipStream_t stream)
{
  (void)in_sizes; (void)n_in; (void)out_size; (void)ws_size;
  const float* x     = (const float*)d_in[0];
  const float* fx    = (const float*)d_in[1];
  const float* ln1_g = (const float*)d_in[2];
  const float* ln1_b = (const float*)d_in[3];
  const float* Wq    = (const float*)d_in[4];
  const float* Wk    = (const float*)d_in[5];
  const float* Wv    = (const float*)d_in[6];
  const float* Wo    = (const float*)d_in[7];
  const float* bo    = (const float*)d_in[8];
  const float* ln2_g = (const float*)d_in[9];
  const float* ln2_b = (const float*)d_in[10];
  const float* mW1   = (const float*)d_in[11];
  const float* mb1   = (const float*)d_in[12];
  const float* mW2   = (const float*)d_in[13];
  const float* mb2   = (const float*)d_in[14];
  const float* pW1   = (const float*)d_in[15];
  const float* pb1   = (const float*)d_in[16];
  const float* pW2   = (const float*)d_in[17];
  const float* pb2   = (const float*)d_in[18];
  const float* mu    = (const float*)d_in[19];
  const float* ln3_g = (const float*)d_in[20];
  const float* ln3_b = (const float*)d_in[21];
  const float* m2W1  = (const float*)d_in[22];
  const float* m2b1  = (const float*)d_in[23];
  const float* m2W2  = (const float*)d_in[24];
  const float* m2b2  = (const float*)d_in[25];

  char* wsb = (char*)d_ws;
  u16* wt    = (u16*)wsb;
  u16* WQKVT = wt + 0;          // 768x256
  u16* WOT   = wt + 196608;     // 256x256
  u16* W1T   = wt + 262144;     // 1024x256
  u16* W2T   = wt + 524288;     // 256x1024
  u16* PW1T  = wt + 786432;     // 256x256
  u16* PW2T  = wt + 851968;     // 128x256 (64 valid)
  u16* M2W1T = wt + 884736;     // 1024x256
  u16* M2W2T = wt + 1146880;    // 256x1024

  constexpr size_t OFF_H      = 2818048;                 // h bf16 [57856,256] (29.6MB)
  constexpr size_t OFF_QKV    = 32440320;                // qkv/m1 bf16 region (118.5MB)
  constexpr size_t OFF_ATT    = 150929408;               // qs bf16 [57872,256] / x2 bf16 [57856,256]
  constexpr size_t OFF_SPART2 = 180551680;               // f32 [64,32,32]
  constexpr size_t OFF_XU     = 180813824;               // x_ f32 [57856,64] (14.8MB)
  constexpr size_t OFF_CTXP   = OFF_XU;                  // alias: f32 [64,32,1024]
  constexpr size_t OFF_CTX    = OFF_XU + 8388608;        // alias: f32 [64,1024]
  constexpr size_t OFF_XW     = 195624960;               // xw bf16 [57800,64]
  constexpr size_t OFF_XWS    = 203023360;               // xws bf16 [57872,64] (padded)
  constexpr size_t OFF_W2BT   = 210430976;               // bf16 [8,256,256] (1MB)
  // aliases into dead regions:
  constexpr size_t OFF_COVP   = OFF_H;                   // f32 [512,4096] - h dead here
  constexpr size_t OFF_COV    = OFF_H + 8388608;
  constexpr size_t OFF_LINV   = OFF_H + 8404992;
  constexpr size_t OFF_C2P    = OFF_QKV;                 // f32 [8,32,256,64] - m1 dead here
  constexpr size_t OFF_C2T    = OFF_QKV + 16777216;      // bf16 [8,256,64]

  u16* h     = (u16*)(wsb + OFF_H);
  u16* qkvb  = (u16*)(wsb + OFF_QKV);
  u16* m1    = qkvb;
  u16* attb  = (u16*)(wsb + OFF_ATT);   // x2 bf16 region
  u16* qsb   = (u16*)(wsb + OFF_ATT);   // qs bf16 (earlier lifetime)
  float* spart2= (float*)(wsb + OFF_SPART2);
  float* ctxp  = (float*)(wsb + OFF_CTXP);
  float* ctxb  = (float*)(wsb + OFF_CTX);
  float* xu    = (float*)(wsb + OFF_XU);
  u16*  xwb    = (u16*)(wsb + OFF_XW);
  u16*  xwsb   = (u16*)(wsb + OFF_XWS);
  float* covp  = (float*)(wsb + OFF_COVP);
  float* cov   = (float*)(wsb + OFF_COV);
  float* Linv  = (float*)(wsb + OFF_LINV);
  float* c2p   = (float*)(wsb + OFF_C2P);
  u16*  c2t    = (u16*)(wsb + OFF_C2T);
  u16*  w2bt   = (u16*)(wsb + OFF_W2BT);

  float* outx  = (float*)d_out;
  float* outfx = outx + 14796800;

  // ---- weight prep: one batched dispatch ----
  WJobs wj;
  wj.src[0]=Wq;   wj.dst[0]=WQKVT;          wj.K[0]=256;  wj.N[0]=256;
  wj.src[1]=Wk;   wj.dst[1]=WQKVT+65536;    wj.K[1]=256;  wj.N[1]=256;
  wj.src[2]=Wv;   wj.dst[2]=WQKVT+131072;   wj.K[2]=256;  wj.N[2]=256;
  wj.src[3]=Wo;   wj.dst[3]=WOT;            wj.K[3]=256;  wj.N[3]=256;
  wj.src[4]=mW1;  wj.dst[4]=W1T;            wj.K[4]=256;  wj.N[4]=1024;
  wj.src[5]=mW2;  wj.dst[5]=W2T;            wj.K[5]=1024; wj.N[5]=256;
  wj.src[6]=pW1;  wj.dst[6]=PW1T;           wj.K[6]=256;  wj.N[6]=256;
  wj.src[7]=pW2;  wj.dst[7]=PW2T;           wj.K[7]=256;  wj.N[7]=64;
  wj.src[8]=m2W1; wj.dst[8]=M2W1T;          wj.K[8]=256;  wj.N[8]=1024;
  wj.src[9]=m2W2; wj.dst[9]=M2W2T;          wj.K[9]=1024; wj.N[9]=256;
  wtrans_all<<<dim3(32,32,10),256,0,stream>>>(wj);

  // ---- attention block ----
  ln_kernel<<<14450,256,0,stream>>>(x, ln1_g, ln1_b, h, NTOK);
  gemm3<false,false,false,false,true><<<dim3(452*6,1,1),512,0,stream>>>(
      h, WQKVT, nullptr, nullptr, nullptr, qkvb, NTOK, 768, 256, 6, 0,0,0);
  qsoftmax<<<dim3(1807,8),256,0,stream>>>(qkvb, qsb);
  ctx_part<<<dim3(32,64),256,0,stream>>>(qkvb, ctxp, spart2);
  ctx_red<<<64,256,0,stream>>>(ctxp, spart2, ctxb);
  ctx_wo<<<dim3(8,8),256,0,stream>>>(ctxb, WOT, w2bt);
  // x1[b] = qs[b] @ W2b[b] + bo + x[b]  (batched; attention apply folded into GEMM)
  gemm3<true,true,false,true,false><<<dim3(57*2,1,8),512,0,stream>>>(
      qsb, w2bt, bo, x, outx, nullptr, NSEQ, 256, 256, 2,
      (long)NSEQ*256, 256*256, (long)NSEQ*256);

  // ---- MLP block ----
  ln_kernel<<<14450,256,0,stream>>>(outx, ln2_g, ln2_b, h, NTOK);
  gemm3<true,false,true,false,true><<<dim3(452*8,1,1),512,0,stream>>>(
      h, W1T, mb1, nullptr, nullptr, m1, NTOK, 1024, 256, 8, 0,0,0);
  gemm3<true,true,false,true,true><<<dim3(452*2,1,1),512,0,stream>>>(
      m1, W2T, mb2, outx, outx, attb, NTOK, 256, 1024, 2, 0,0,0);

  // ---- low-rank projection ----
  gemm3<true,false,true,false,true><<<dim3(452*2,1,1),512,0,stream>>>(
      attb, PW1T, pb1, nullptr, nullptr, h, NTOK, 256, 256, 2, 0,0,0);
  gemm3<true,false,false,true,false><<<dim3(452,1,1),512,0,stream>>>(
      h, PW2T, pb2, nullptr, xu, nullptr, NTOK, 64, 256, 1, 0,0,0);

  // ---- covariance + Cholesky whitening ----
  cov_part<<<512,256,0,stream>>>(xu, covp);
  cov_red<<<64,256,0,stream>>>(covp, cov);
  chol_inv<<<1,64,0,stream>>>(cov, Linv);
  whiten<<<3613,256,0,stream>>>(xu, Linv, mu, xwb, xwsb);

  // ---- low-rank operator on fx ----
  ctx2_part<<<dim3(32,8),512,0,stream>>>(xwb, fx, c2p);
  ctx2_red<<<dim3(16,8),256,0,stream>>>(c2p, c2t);
  gemm3<false,false,false,true,false><<<dim3(57*2,1,8),512,0,stream>>>(
      xwsb, c2t, nullptr, nullptr, outfx, nullptr, NSEQ, 256, 64, 2,
      (long)NSEQ*64, 256*64, (long)NSEQ*256);

  // ---- final MLP on fx ----
  ln_kernel<<<14450,256,0,stream>>>(outfx, ln3_g, ln3_b, h, NTOK);
  gemm3<true,false,true,false,true><<<dim3(452*8,1,1),512,0,stream>>>(
      h, M2W1T, m2b1, nullptr, nullptr, m1, NTOK, 1024, 256, 8, 0,0,0);
  gemm3<true,false,false,true,false><<<dim3(452*2,1,1),512,0,stream>>>(
      m1, M2W2T, m2b2, nullptr, outfx, nullptr, NTOK, 256, 1024, 2, 0,0,0);
}

// Round 13
// 750.742 us; speedup vs baseline: 1.0133x; 1.0133x over previous
//
#include <hip/hip_runtime.h>
#include <math.h>

typedef unsigned short u16;
typedef unsigned int u32;
typedef float f32x4 __attribute__((ext_vector_type(4)));
typedef __bf16 bf16x8 __attribute__((ext_vector_type(8)));

#define NTOK 57800   // B*N
#define NSEQ 7225
#define NBATCH 8

static __device__ __forceinline__ float bf2f(u16 u){ u32 x=((u32)u)<<16; float f; __builtin_memcpy(&f,&x,4); return f; }
// f32->bf16 RNE via hardware convert
static __device__ __forceinline__ u16 f2bf(float f){ __bf16 h = (__bf16)f; u16 u; __builtin_memcpy(&u,&h,2); return u; }
// fast gelu: 0.5*v*(1+tanh(y)) == v*sigmoid(2y); ~8 VALU ops, no branch
static __device__ __forceinline__ float gelu_f(float v){
  float t = v * v;
  float w = fmaf(t, -0.07135481627f, -1.5957691216f);
  float e = __expf(w * v);
  return v * __builtin_amdgcn_rcpf(1.0f + e);
}

static __device__ __forceinline__ void gl16(const u16* g, u16* l){
  __builtin_amdgcn_global_load_lds((const __attribute__((address_space(1))) void*)g,
                                   (__attribute__((address_space(3))) void*)l, 16, 0, 0);
}

// broadcast lane 'lane' of v to all lanes (lane uniform / compile-time)
static __device__ __forceinline__ float rdlane(float v, int lane){
  int i; __builtin_memcpy(&i,&v,4);
  int r = __builtin_amdgcn_readlane(i, lane);
  float f; __builtin_memcpy(&f,&r,4);
  return f;
}

// ---------- batched LDS-tiled weight transpose + bf16 cast: dst[n*K+k] = src[k*N+n] ----------
struct WJobs { const float* src[10]; u16* dst[10]; int K[10]; int N[10]; };
__global__ __launch_bounds__(256) void wtrans_all(WJobs j){
  int z = blockIdx.z;
  int K = j.K[z], N = j.N[z];
  int bk = blockIdx.x*32, bn = blockIdx.y*32;
  if (bk >= K || bn >= N) return;
  const float* src = j.src[z];
  u16* dst = j.dst[z];
  __shared__ float t[32][33];
  int tx = threadIdx.x&31, ty = threadIdx.x>>5;
  #pragma unroll
  for (int u=0;u<4;u++){
    int k = bk+ty+u*8, n = bn+tx;
    if (k<K && n<N) t[ty+u*8][tx] = src[(long)k*N+n];
  }
  __syncthreads();
  #pragma unroll
  for (int u=0;u<4;u++){
    int n = bn+ty+u*8, k = bk+tx;
    if (n<N && k<K) dst[(long)n*K+k] = f2bf(t[tx][ty+u*8]);
  }
}

// ---------- LayerNorm (rows x 256) fp32 -> bf16, one wave per row ----------
__global__ __launch_bounds__(256) void ln_kernel(const float* __restrict__ in, const float* __restrict__ g,
                                                 const float* __restrict__ b, u16* __restrict__ out, int rows){
  int wid = threadIdx.x>>6, lane = threadIdx.x&63;
  int row = blockIdx.x*4 + wid;
  if (row >= rows) return;
  const float4 xv = *reinterpret_cast<const float4*>(in + (long)row*256 + lane*4);
  float s = xv.x+xv.y+xv.z+xv.w;
  float s2 = xv.x*xv.x+xv.y*xv.y+xv.z*xv.z+xv.w*xv.w;
  #pragma unroll
  for (int o=32;o;o>>=1){ s += __shfl_xor(s,o,64); s2 += __shfl_xor(s2,o,64); }
  float mean = s*(1.f/256.f);
  float var = fmaxf(s2*(1.f/256.f) - mean*mean, 0.f);
  float rstd = rsqrtf(var + 1e-5f);
  float4 gv = *reinterpret_cast<const float4*>(g + lane*4);
  float4 bv = *reinterpret_cast<const float4*>(b + lane*4);
  ushort4 o4;
  o4.x = f2bf((xv.x-mean)*rstd*gv.x + bv.x);
  o4.y = f2bf((xv.y-mean)*rstd*gv.y + bv.y);
  o4.z = f2bf((xv.z-mean)*rstd*gv.z + bv.z);
  o4.w = f2bf((xv.w-mean)*rstd*gv.w + bv.w);
  *reinterpret_cast<ushort4*>(out + (long)row*256 + lane*4) = o4;
}

// ---------- bf16 MFMA GEMM v6 (session-best config): C = A[M,K] @ Bt[N,K]^T ----------
// 128x128 tile, 8 waves (512 thr) of 64x32 each, BK=64, 64 KB LDS dbuf ->
// 2 blocks/CU = 16 waves/CU. Counted-vmcnt 2-deep prefetch (T4): wait vmcnt(4)
// so next tile's 4 loads stay in flight across the raw barrier; vmcnt(0) only
// on the last tile. (Tested and rejected: BK=32 1-deep, BK=32 3-deep, NT
// stores, per-MFMA L2 B-reads, fused MLP — all neutral or regressed.)
template<bool BIASF, bool RESF, bool GELUF, bool OF32, bool OBF16>
__global__ __launch_bounds__(512) void gemm3(const u16* __restrict__ A, const u16* __restrict__ Bt,
    const float* __restrict__ bias, const float* __restrict__ resid,
    float* __restrict__ outF, u16* __restrict__ outB,
    int M, int N, int K, int gn, long aB, long bB, long cB)
{
  __shared__ __align__(16) u16 lds[2][2][8192];   // [dbuf][A/B][128*64] = 64 KB
  int nwg = gridDim.x, bid = blockIdx.x;
  int qx = nwg>>3, rx = nwg&7;
  int xcd = bid&7, lin = bid>>3;
  int swz = (xcd<rx)? (xcd*(qx+1)+lin) : (rx + xcd*qx + lin);  // bijective (m204)
  int mi_ = swz/gn;
  int m0 = mi_*128, n0 = (swz - mi_*gn)*128;

  const u16* Ab  = A  + (long)blockIdx.z*aB;
  const u16* Btb = Bt + (long)blockIdx.z*bB;
  long coff = (long)blockIdx.z*cB;
  int tid = threadIdx.x, w = tid>>6, l = tid&63;
  int lr = l>>3;
  int csrc = (((l&7) ^ lr) << 3);
  int l15 = l&15, lq = l>>4;
  int wm = (w>>2)*64, wn = (w&3)*32;     // 2M x 4N waves, 64x32 per wave
  int sx = (l15&7)<<3;

  f32x4 acc[4][2];
  #pragma unroll
  for (int a=0;a<4;a++)
    #pragma unroll
    for (int b2=0;b2<2;b2++)
      #pragma unroll
      for (int r2=0;r2<4;r2++) acc[a][b2][r2]=0.f;

  int nt = K>>6;

  auto STAGE = [&](int k0, int bufi){
    #pragma unroll
    for (int u=0;u<2;u++){
      int rr = w*16 + u*8;
      gl16(Ab  + (long)(m0+rr+lr)*K + k0 + csrc, &lds[bufi][0][0] + rr*64 + l*8);
      gl16(Btb + (long)(n0+rr+lr)*K + k0 + csrc, &lds[bufi][1][0] + rr*64 + l*8);
    }
  };

  STAGE(0, 0);
  if (nt > 1) STAGE(64, 1);
  for (int t=0; t<nt; t++){
    int cur = t&1;
    // wait only for THIS tile's 4 loads; the next tile's 4 keep flying (T4).
    if (t+1 < nt) asm volatile("s_waitcnt vmcnt(4)" ::: "memory");
    else          asm volatile("s_waitcnt vmcnt(0)" ::: "memory");
    __builtin_amdgcn_s_barrier();
    __builtin_amdgcn_sched_barrier(0);
    #pragma unroll
    for (int ks=0;ks<2;ks++){
      bf16x8 af[4], bfv[2];
      int ko = ks*32 + lq*8;
      #pragma unroll
      for (int mi=0;mi<4;mi++)
        af[mi]  = *reinterpret_cast<const bf16x8*>(&lds[cur][0][0] + (wm+mi*16+l15)*64 + (ko ^ sx));
      #pragma unroll
      for (int ni=0;ni<2;ni++)
        bfv[ni] = *reinterpret_cast<const bf16x8*>(&lds[cur][1][0] + (wn+ni*16+l15)*64 + (ko ^ sx));
      #pragma unroll
      for (int mi=0;mi<4;mi++)
        #pragma unroll
        for (int ni=0;ni<2;ni++)
          acc[mi][ni] = __builtin_amdgcn_mfma_f32_16x16x32_bf16(bfv[ni], af[mi], acc[mi][ni], 0,0,0);
    }
    if (t+2 < nt){
      __builtin_amdgcn_s_barrier();    // all waves done reading buf[cur] before overwrite
      STAGE((t+2)<<6, cur);
    }
  }

  #pragma unroll
  for (int mi=0;mi<4;mi++){
    int row = m0 + wm + mi*16 + l15;
    if (row >= M) continue;
    #pragma unroll
    for (int ni=0;ni<2;ni++){
      int col0 = n0 + wn + ni*16 + lq*4;
      if (col0 >= N) continue;
      f32x4 v = acc[mi][ni];
      if (BIASF){
        const float4 bv = *reinterpret_cast<const float4*>(bias + col0);
        v[0]+=bv.x; v[1]+=bv.y; v[2]+=bv.z; v[3]+=bv.w;
      }
      long idx = (long)row*N + col0;
      if (RESF){
        const float4 rv = *reinterpret_cast<const float4*>(resid + coff + idx);
        v[0]+=rv.x; v[1]+=rv.y; v[2]+=rv.z; v[3]+=rv.w;
      }
      if (GELUF){
        #pragma unroll
        for (int r2=0;r2<4;r2++) v[r2] = gelu_f(v[r2]);
      }
      if (OF32){
        float4 o; o.x=v[0]; o.y=v[1]; o.z=v[2]; o.w=v[3];
        *reinterpret_cast<float4*>(outF + coff + idx) = o;
      }
      if (OBF16){
        ushort4 o; o.x=f2bf(v[0]); o.y=f2bf(v[1]); o.z=f2bf(v[2]); o.w=f2bf(v[3]);
        *reinterpret_cast<ushort4*>(outB + coff + idx) = o;
      }
    }
  }
}

// ---------- ctx[b,h,d,e] partials + fused k colsum partials ----------
// 16-row tiles, uint2 (4x bf16, 8B/lane) staging loads; same n-ascending
// accumulation order as the 8-row scalar version -> bit-identical.
__global__ __launch_bounds__(256) void ctx_part(const u16* __restrict__ qkvb, float* __restrict__ part,
                                                float* __restrict__ spart2){
  int ch = blockIdx.x, bh = blockIdx.y; int b = bh>>3, h = bh&7;
  __shared__ float ek[16][32], vl[16][32];
  int tid = threadIdx.x;
  int d = tid&31, eg = (tid>>5)*4;
  float acc[4] = {0.f,0.f,0.f,0.f};
  float ssum = 0.f;
  int n0 = ch*226; int n1 = n0+226; if (n1 > NSEQ) n1 = NSEQ;
  int lr = tid>>4, le = (tid&15)*4;            // row 0..15, elem-quad 0..60
  for (int nb=n0; nb<n1; nb+=16){
    int n = nb + lr;
    float f0=0.f, f1=0.f, f2=0.f, f3=0.f;
    if (n < n1){
      long base = ((long)(b*NSEQ+n))*768 + h*32;
      const u16* src = (le < 32) ? (qkvb + base + 256 + le) : (qkvb + base + 512 + (le-32));
      uint2 pk = *reinterpret_cast<const uint2*>(src);
      f0 = bf2f((u16)(pk.x&0xffffu)); f1 = bf2f((u16)(pk.x>>16));
      f2 = bf2f((u16)(pk.y&0xffffu)); f3 = bf2f((u16)(pk.y>>16));
      if (le < 32){ f0=__expf(f0); f1=__expf(f1); f2=__expf(f2); f3=__expf(f3); }
    }
    if (le < 32){ ek[lr][le]=f0; ek[lr][le+1]=f1; ek[lr][le+2]=f2; ek[lr][le+3]=f3; }
    else        { int vv=le-32; vl[lr][vv]=f0; vl[lr][vv+1]=f1; vl[lr][vv+2]=f2; vl[lr][vv+3]=f3; }
    __syncthreads();
    #pragma unroll
    for (int r=0;r<16;r++){
      float kv = ek[r][d];
      ssum += kv;
      #pragma unroll
      for (int j=0;j<4;j++) acc[j] += kv * vl[r][eg+j];
    }
    __syncthreads();
  }
  #pragma unroll
  for (int j=0;j<4;j++) part[((long)(bh*32+ch))*1024 + d*32 + eg + j] = acc[j];
  if (tid < 32) spart2[(bh*32+ch)*32 + d] = ssum;
}
__global__ void ctx_red(const float* __restrict__ part, const float* __restrict__ spart2,
                        float* __restrict__ ctx){
  int bh = blockIdx.x;
  __shared__ float sinvl[32];
  int tid = threadIdx.x;
  if (tid < 32){
    float s=0.f;
    for (int ch=0;ch<32;ch++) s += spart2[(bh*32+ch)*32 + tid];
    sinvl[tid] = 1.0f/s;
  }
  __syncthreads();
  for (int idx=tid; idx<1024; idx+=256){
    float s=0.f;
    for (int ch=0;ch<32;ch++) s += part[((long)(bh*32+ch))*1024 + idx];
    ctx[(long)bh*1024 + idx] = s * sinvl[idx>>5];
  }
}

// ---------- q feature-softmax: qs[n,c] = exp(q)/sum_head(exp) * DH^-0.5, bf16 out ----------
__global__ __launch_bounds__(256) void qsoftmax(const u16* __restrict__ qkvb, u16* __restrict__ qsb){
  int wid = threadIdx.x>>6, lane = threadIdx.x&63;
  int n = blockIdx.x*4 + wid;
  int b = blockIdx.y;
  if (n >= NSEQ) return;
  const ushort4 qv = *reinterpret_cast<const ushort4*>(qkvb + ((long)(b*NSEQ+n))*768 + lane*4);
  float e0 = __expf(bf2f(qv.x)), e1 = __expf(bf2f(qv.y)),
        e2 = __expf(bf2f(qv.z)), e3 = __expf(bf2f(qv.w));
  float s = e0+e1+e2+e3;
  s += __shfl_xor(s,1,64); s += __shfl_xor(s,2,64); s += __shfl_xor(s,4,64);
  float r = 0.17677669529663687f / s;
  ushort4 o; o.x=f2bf(e0*r); o.y=f2bf(e1*r); o.z=f2bf(e2*r); o.w=f2bf(e3*r);
  *reinterpret_cast<ushort4*>(qsb + ((long)(b*NSEQ+n))*256 + lane*4) = o;
}

// ---------- merged weight: w2bt[b][j][h*32+d] = sum_e ctx[b,h,d,e]*WOT[j][h*32+e] ----------
__global__ __launch_bounds__(256) void ctx_wo(const float* __restrict__ ctx, const u16* __restrict__ wot,
                                              u16* __restrict__ w2bt){
  int jg = blockIdx.x, b = blockIdx.y;
  int j0 = jg*32;
  __shared__ u16 wol[32][256];
  int tid = threadIdx.x;
  {
    int r = tid>>3, c = (tid&7)*32;
    const uint4* src = reinterpret_cast<const uint4*>(wot + (j0+r)*256 + c);
    uint4* dst = reinterpret_cast<uint4*>(&wol[r][c]);
    dst[0]=src[0]; dst[1]=src[1]; dst[2]=src[2]; dst[3]=src[3];
  }
  int h = tid>>5, d = tid&31;
  float creg[32];
  {
    const float4* cp = reinterpret_cast<const float4*>(ctx + (long)(b*8+h)*1024 + d*32);
    #pragma unroll
    for (int u=0;u<8;u++){ float4 v = cp[u]; creg[u*4]=v.x; creg[u*4+1]=v.y; creg[u*4+2]=v.z; creg[u*4+3]=v.w; }
  }
  __syncthreads();
  for (int jj=0;jj<32;jj++){
    const uint4* wp = reinterpret_cast<const uint4*>(&wol[jj][h*32]);
    float acc = 0.f;
    #pragma unroll
    for (int u=0;u<4;u++){
      uint4 wv = wp[u];
      acc += bf2f((u16)(wv.x&0xffffu))*creg[u*8+0] + bf2f((u16)(wv.x>>16))*creg[u*8+1]
           + bf2f((u16)(wv.y&0xffffu))*creg[u*8+2] + bf2f((u16)(wv.y>>16))*creg[u*8+3]
           + bf2f((u16)(wv.z&0xffffu))*creg[u*8+4] + bf2f((u16)(wv.z>>16))*creg[u*8+5]
           + bf2f((u16)(wv.w&0xffffu))*creg[u*8+6] + bf2f((u16)(wv.w>>16))*creg[u*8+7];
    }
    w2bt[((long)b*256 + j0+jj)*256 + tid] = f2bf(acc);
  }
}

// ---------- cov partials: 512 chunks, reg-prefetch dbuf, broadcast-b128 inner ----------
__global__ __launch_bounds__(256) void cov_part(const float* __restrict__ xu, float* __restrict__ part){
  int ch = blockIdx.x;
  __shared__ float xl[2][8][64];
  int tid = threadIdx.x;
  int i = tid&63, jg = (tid>>6)*16;
  int lrow = tid>>5, lcol = (tid&31)*2;
  float acc[16];
  #pragma unroll
  for (int j=0;j<16;j++) acc[j]=0.f;
  int n0 = ch*113;
  const int NT = 15;
  float2 xr2;
  auto LOAD = [&](int t){
    int n = n0 + t*8 + lrow;
    if (n < n0+113 && n < NTOK) xr2 = *reinterpret_cast<const float2*>(xu + (long)n*64 + lcol);
    else { xr2.x = 0.f; xr2.y = 0.f; }
  };
  LOAD(0);
  for (int t=0; t<NT; t++){
    int cur = t&1;
    xl[cur][lrow][lcol] = xr2.x; xl[cur][lrow][lcol+1] = xr2.y;
    __syncthreads();
    if (t+1 < NT) LOAD(t+1);
    #pragma unroll
    for (int r=0;r<8;r++){
      float xv = xl[cur][r][i];
      const float4* fb = reinterpret_cast<const float4*>(&xl[cur][r][jg]);
      float4 f0=fb[0], f1=fb[1], f2=fb[2], f3=fb[3];
      acc[0]+=xv*f0.x; acc[1]+=xv*f0.y; acc[2]+=xv*f0.z; acc[3]+=xv*f0.w;
      acc[4]+=xv*f1.x; acc[5]+=xv*f1.y; acc[6]+=xv*f1.z; acc[7]+=xv*f1.w;
      acc[8]+=xv*f2.x; acc[9]+=xv*f2.y; acc[10]+=xv*f2.z; acc[11]+=xv*f2.w;
      acc[12]+=xv*f3.x; acc[13]+=xv*f3.y; acc[14]+=xv*f3.z; acc[15]+=xv*f3.w;
    }
    __syncthreads();
  }
  #pragma unroll
  for (int j=0;j<16;j++) part[(long)ch*4096 + (jg+j)*64 + i] = acc[j];
}
__global__ void cov_red(const float* __restrict__ part, float* __restrict__ cov){
  __shared__ float red[4][64];
  int o = blockIdx.x*64 + (threadIdx.x&63);
  int sl = threadIdx.x>>6;
  float s=0.f;
  for (int ch=sl; ch<512; ch+=4) s += part[(long)ch*4096 + o];
  if (sl>0) red[sl][threadIdx.x&63] = s;
  __syncthreads();
  if (sl==0){
    s += red[1][threadIdx.x&63] + red[2][threadIdx.x&63] + red[3][threadIdx.x&63];
    cov[o] = s * (1.0f/57800.0f);
  }
}

// ---------- Cholesky of 64x64 + lower-triangular inverse (register-resident) ----------
__global__ __launch_bounds__(64) void chol_inv(const float* __restrict__ cov, float* __restrict__ Linv){
  int t = threadIdx.x;
  float r[64];
  #pragma unroll
  for (int k=0;k<16;k++){
    float4 v4 = *reinterpret_cast<const float4*>(cov + (long)t*64 + k*4);
    r[k*4]=v4.x; r[k*4+1]=v4.y; r[k*4+2]=v4.z; r[k*4+3]=v4.w;
  }
  float dinv[64];
  #pragma unroll
  for (int j=0;j<64;j++){
    float ajj = rdlane(r[j], j);
    float ljj = sqrtf(fmaxf(ajj, 1e-20f));
    float rinv = 1.0f / ljj;
    dinv[j] = rinv;
    float ltj = r[j] * rinv;
    r[j] = ltj;
    #pragma unroll
    for (int k=j+1;k<64;k++){
      float lkj = rdlane(ltj, k);
      r[k] -= ltj * lkj;
    }
  }
  float v[64];
  #pragma unroll
  for (int k=0;k<64;k++) v[k] = (k==t) ? 1.f : 0.f;
  #pragma unroll
  for (int i=0;i<64;i++){
    float xi = v[i] * dinv[i];
    Linv[i*64 + t] = xi;
    #pragma unroll
    for (int k=i+1;k<64;k++){
      v[k] -= rdlane(r[i], k) * xi;
    }
  }
}

// ---------- whiten: xw[n,i] = sum_j x_[n,j]*Linv[i,j]; xws = xw*softplus(mu) ----------
__global__ __launch_bounds__(256) void whiten(const float* __restrict__ xu, const float* __restrict__ Linv,
                                              const float* __restrict__ mu, u16* __restrict__ xw, u16* __restrict__ xws){
  __shared__ float Ll[64][65];
  int tid = threadIdx.x;
  for (int u=0; u<16; u++){ int idx = u*256+tid; Ll[idx>>6][idx&63] = Linv[idx]; }
  __syncthreads();
  int wid = tid>>6, lane = tid&63;
  float m = mu[lane];
  float sp = (m > 20.f)? m : log1pf(expf(m));
  for (int rr=0; rr<4; rr++){
    int row = blockIdx.x*16 + wid*4 + rr;
    if (row >= NTOK) continue;
    float xj = xu[(long)row*64 + lane];
    float s = 0.f;
    #pragma unroll
    for (int j=0;j<64;j++) s += __shfl(xj, j, 64) * Ll[lane][j];
    xw[(long)row*64+lane]  = f2bf(s);
    xws[(long)row*64+lane] = f2bf(s * sp);
  }
}

// ---------- ctx2 partials: one block per (chunk,batch), fx read once; 8 waves ----------
__global__ __launch_bounds__(512) void ctx2_part(const u16* __restrict__ xw, const float* __restrict__ fx,
                                                 float* __restrict__ part){
  int ch = blockIdx.x, b = blockIdx.y;
  __shared__ float xwlf[2][16][64];    // 8 KB
  __shared__ float fxl[2][16][256];    // 32 KB
  int tid = threadIdx.x;
  int p = tid&63, jg = ((tid>>6)&7)*32;       // 8 wave-groups x 32 c = 256
  int lrow = tid>>5, lcol = (tid&31)*8, xcol = (tid&31)*2;
  float acc[32];
  #pragma unroll
  for (int j=0;j<32;j++) acc[j]=0.f;
  int n0 = ch*226;
  int n1 = n0+226; if (n1 > NSEQ) n1 = NSEQ;
  const int NT = 15;                           // 15*16 = 240 >= 226
  float4 fra, frb; u32 xr;
  auto LOAD = [&](int t){
    int n = n0 + t*16 + lrow;
    if (n < n1){
      const float4* fp = reinterpret_cast<const float4*>(fx + ((long)b*NSEQ+n)*256 + lcol);
      fra = fp[0]; frb = fp[1];
      xr = *reinterpret_cast<const u32*>(xw + ((long)b*NSEQ+n)*64 + xcol);
    } else {
      fra.x=0.f; fra.y=0.f; fra.z=0.f; fra.w=0.f;
      frb.x=0.f; frb.y=0.f; frb.z=0.f; frb.w=0.f;
      xr = 0;
    }
  };
  LOAD(0);
  for (int t=0; t<NT; t++){
    int cur = t&1;
    xwlf[cur][lrow][xcol]   = bf2f((u16)(xr&0xffffu));
    xwlf[cur][lrow][xcol+1] = bf2f((u16)(xr>>16));
    *reinterpret_cast<float4*>(&fxl[cur][lrow][lcol])   = fra;
    *reinterpret_cast<float4*>(&fxl[cur][lrow][lcol+4]) = frb;
    __syncthreads();
    if (t+1 < NT) LOAD(t+1);
    #pragma unroll
    for (int r=0;r<16;r++){
      float xv = xwlf[cur][r][p];
      const float4* fb = reinterpret_cast<const float4*>(&fxl[cur][r][jg]);  // wave-uniform -> broadcast
      #pragma unroll
      for (int c4=0;c4<8;c4++){
        float4 f = fb[c4];
        acc[c4*4+0]+=xv*f.x; acc[c4*4+1]+=xv*f.y; acc[c4*4+2]+=xv*f.z; acc[c4*4+3]+=xv*f.w;
      }
    }
    __syncthreads();
  }
  long base = ((long)(b*32+ch)*256 + jg)*64 + p;
  #pragma unroll
  for (int j=0;j<32;j++) part[base + (long)j*64] = acc[j];
}
__global__ void ctx2_red(const float* __restrict__ part, u16* __restrict__ c2t){
  int b = blockIdx.y;
  int idx0 = blockIdx.x*1024 + threadIdx.x;
  #pragma unroll
  for (int u=0;u<4;u++){
    int id = idx0 + u*256;
    float s=0.f;
    for (int ch=0;ch<32;ch++) s += part[(long)(b*32+ch)*16384 + id];
    c2t[(long)b*16384 + id] = f2bf(s);
  }
}

// ===================== host launch =====================
extern "C" void kernel_launch(void* const* d_in, const int* in_sizes, int n_in,
                              void* d_out, int out_size, void* d_ws, size_t ws_size,
                              hipStream_t stream)
{
  (void)in_sizes; (void)n_in; (void)out_size; (void)ws_size;
  const float* x     = (const float*)d_in[0];
  const float* fx    = (const float*)d_in[1];
  const float* ln1_g = (const float*)d_in[2];
  const float* ln1_b = (const float*)d_in[3];
  const float* Wq    = (const float*)d_in[4];
  const float* Wk    = (const float*)d_in[5];
  const float* Wv    = (const float*)d_in[6];
  const float* Wo    = (const float*)d_in[7];
  const float* bo    = (const float*)d_in[8];
  const float* ln2_g = (const float*)d_in[9];
  const float* ln2_b = (const float*)d_in[10];
  const float* mW1   = (const float*)d_in[11];
  const float* mb1   = (const float*)d_in[12];
  const float* mW2   = (const float*)d_in[13];
  const float* mb2   = (const float*)d_in[14];
  const float* pW1   = (const float*)d_in[15];
  const float* pb1   = (const float*)d_in[16];
  const float* pW2   = (const float*)d_in[17];
  const float* pb2   = (const float*)d_in[18];
  const float* mu    = (const float*)d_in[19];
  const float* ln3_g = (const float*)d_in[20];
  const float* ln3_b = (const float*)d_in[21];
  const float* m2W1  = (const float*)d_in[22];
  const float* m2b1  = (const float*)d_in[23];
  const float* m2W2  = (const float*)d_in[24];
  const float* m2b2  = (const float*)d_in[25];

  char* wsb = (char*)d_ws;
  u16* wt    = (u16*)wsb;
  u16* WQKVT = wt + 0;          // 768x256
  u16* WOT   = wt + 196608;     // 256x256
  u16* W1T   = wt + 262144;     // 1024x256
  u16* W2T   = wt + 524288;     // 256x1024
  u16* PW1T  = wt + 786432;     // 256x256
  u16* PW2T  = wt + 851968;     // 128x256 (64 valid)
  u16* M2W1T = wt + 884736;     // 1024x256
  u16* M2W2T = wt + 1146880;    // 256x1024

  constexpr size_t OFF_H      = 2818048;                 // h bf16 [57856,256] (29.6MB)
  constexpr size_t OFF_QKV    = 32440320;                // qkv/m1 bf16 region (118.5MB)
  constexpr size_t OFF_ATT    = 150929408;               // qs bf16 [57872,256] / x2 bf16 [57856,256]
  constexpr size_t OFF_SPART2 = 180551680;               // f32 [64,32,32]
  constexpr size_t OFF_XU     = 180813824;               // x_ f32 [57856,64] (14.8MB)
  constexpr size_t OFF_CTXP   = OFF_XU;                  // alias: f32 [64,32,1024]
  constexpr size_t OFF_CTX    = OFF_XU + 8388608;        // alias: f32 [64,1024]
  constexpr size_t OFF_XW     = 195624960;               // xw bf16 [57800,64]
  constexpr size_t OFF_XWS    = 203023360;               // xws bf16 [57872,64] (padded)
  constexpr size_t OFF_W2BT   = 210430976;               // bf16 [8,256,256] (1MB)
  // aliases into dead regions:
  constexpr size_t OFF_COVP   = OFF_H;                   // f32 [512,4096] - h dead here
  constexpr size_t OFF_COV    = OFF_H + 8388608;
  constexpr size_t OFF_LINV   = OFF_H + 8404992;
  constexpr size_t OFF_C2P    = OFF_QKV;                 // f32 [8,32,256,64] - m1 dead here
  constexpr size_t OFF_C2T    = OFF_QKV + 16777216;      // bf16 [8,256,64]

  u16* h     = (u16*)(wsb + OFF_H);
  u16* qkvb  = (u16*)(wsb + OFF_QKV);
  u16* m1    = qkvb;
  u16* attb  = (u16*)(wsb + OFF_ATT);   // x2 bf16 region
  u16* qsb   = (u16*)(wsb + OFF_ATT);   // qs bf16 (earlier lifetime)
  float* spart2= (float*)(wsb + OFF_SPART2);
  float* ctxp  = (float*)(wsb + OFF_CTXP);
  float* ctxb  = (float*)(wsb + OFF_CTX);
  float* xu    = (float*)(wsb + OFF_XU);
  u16*  xwb    = (u16*)(wsb + OFF_XW);
  u16*  xwsb   = (u16*)(wsb + OFF_XWS);
  float* covp  = (float*)(wsb + OFF_COVP);
  float* cov   = (float*)(wsb + OFF_COV);
  float* Linv  = (float*)(wsb + OFF_LINV);
  float* c2p   = (float*)(wsb + OFF_C2P);
  u16*  c2t    = (u16*)(wsb + OFF_C2T);
  u16*  w2bt   = (u16*)(wsb + OFF_W2BT);

  float* outx  = (float*)d_out;
  float* outfx = outx + 14796800;

  // ---- weight prep: one batched dispatch ----
  WJobs wj;
  wj.src[0]=Wq;   wj.dst[0]=WQKVT;          wj.K[0]=256;  wj.N[0]=256;
  wj.src[1]=Wk;   wj.dst[1]=WQKVT+65536;    wj.K[1]=256;  wj.N[1]=256;
  wj.src[2]=Wv;   wj.dst[2]=WQKVT+131072;   wj.K[2]=256;  wj.N[2]=256;
  wj.src[3]=Wo;   wj.dst[3]=WOT;            wj.K[3]=256;  wj.N[3]=256;
  wj.src[4]=mW1;  wj.dst[4]=W1T;            wj.K[4]=256;  wj.N[4]=1024;
  wj.src[5]=mW2;  wj.dst[5]=W2T;            wj.K[5]=1024; wj.N[5]=256;
  wj.src[6]=pW1;  wj.dst[6]=PW1T;           wj.K[6]=256;  wj.N[6]=256;
  wj.src[7]=pW2;  wj.dst[7]=PW2T;           wj.K[7]=256;  wj.N[7]=64;
  wj.src[8]=m2W1; wj.dst[8]=M2W1T;          wj.K[8]=256;  wj.N[8]=1024;
  wj.src[9]=m2W2; wj.dst[9]=M2W2T;          wj.K[9]=1024; wj.N[9]=256;
  wtrans_all<<<dim3(32,32,10),256,0,stream>>>(wj);

  // ---- attention block ----
  ln_kernel<<<14450,256,0,stream>>>(x, ln1_g, ln1_b, h, NTOK);
  gemm3<false,false,false,false,true><<<dim3(452*6,1,1),512,0,stream>>>(
      h, WQKVT, nullptr, nullptr, nullptr, qkvb, NTOK, 768, 256, 6, 0,0,0);
  qsoftmax<<<dim3(1807,8),256,0,stream>>>(qkvb, qsb);
  ctx_part<<<dim3(32,64),256,0,stream>>>(qkvb, ctxp, spart2);
  ctx_red<<<64,256,0,stream>>>(ctxp, spart2, ctxb);
  ctx_wo<<<dim3(8,8),256,0,stream>>>(ctxb, WOT, w2bt);
  // x1[b] = qs[b] @ W2b[b] + bo + x[b]  (batched; attention apply folded into GEMM)
  gemm3<true,true,false,true,false><<<dim3(57*2,1,8),512,0,stream>>>(
      qsb, w2bt, bo, x, outx, nullptr, NSEQ, 256, 256, 2,
      (long)NSEQ*256, 256*256, (long)NSEQ*256);

  // ---- MLP block ----
  ln_kernel<<<14450,256,0,stream>>>(outx, ln2_g, ln2_b, h, NTOK);
  gemm3<true,false,true,false,true><<<dim3(452*8,1,1),512,0,stream>>>(
      h, W1T, mb1, nullptr, nullptr, m1, NTOK, 1024, 256, 8, 0,0,0);
  gemm3<true,true,false,true,true><<<dim3(452*2,1,1),512,0,stream>>>(
      m1, W2T, mb2, outx, outx, attb, NTOK, 256, 1024, 2, 0,0,0);

  // ---- low-rank projection ----
  gemm3<true,false,true,false,true><<<dim3(452*2,1,1),512,0,stream>>>(
      attb, PW1T, pb1, nullptr, nullptr, h, NTOK, 256, 256, 2, 0,0,0);
  gemm3<true,false,false,true,false><<<dim3(452,1,1),512,0,stream>>>(
      h, PW2T, pb2, nullptr, xu, nullptr, NTOK, 64, 256, 1, 0,0,0);

  // ---- covariance + Cholesky whitening ----
  cov_part<<<512,256,0,stream>>>(xu, covp);
  cov_red<<<64,256,0,stream>>>(covp, cov);
  chol_inv<<<1,64,0,stream>>>(cov, Linv);
  whiten<<<3613,256,0,stream>>>(xu, Linv, mu, xwb, xwsb);

  // ---- low-rank operator on fx ----
  ctx2_part<<<dim3(32,8),512,0,stream>>>(xwb, fx, c2p);
  ctx2_red<<<dim3(16,8),256,0,stream>>>(c2p, c2t);
  gemm3<false,false,false,true,false><<<dim3(57*2,1,8),512,0,stream>>>(
      xwsb, c2t, nullptr, nullptr, outfx, nullptr, NSEQ, 256, 64, 2,
      (long)NSEQ*64, 256*64, (long)NSEQ*256);

  // ---- final MLP on fx ----
  ln_kernel<<<14450,256,0,stream>>>(outfx, ln3_g, ln3_b, h, NTOK);
  gemm3<true,false,true,false,true><<<dim3(452*8,1,1),512,0,stream>>>(
      h, M2W1T, m2b1, nullptr, nullptr, m1, NTOK, 1024, 256, 8, 0,0,0);
  gemm3<true,false,false,true,false><<<dim3(452*2,1,1),512,0,stream>>>(
      m1, M2W2T, m2b2, nullptr, outfx, nullptr, NTOK, 256, 1024, 2, 0,0,0);
}